// Round 1
// baseline (45.891 us; speedup 1.0000x reference)
//
#include <hip/hip_runtime.h>
#include <hip/hip_bf16.h>

#define BB 16
#define FF 128
#define HH 144
#define EE 24
#define C0C 12

// Workspace layout (floats):
//   num_t: [B][F+1][H]  (cumsum of p*d, with leading zero row)
//   den_t: [B][F+1][H]  (cumsum of p,   with leading zero row)
#define TABLE_ELEMS (BB * (FF + 1) * HH)

__global__ __launch_bounds__(128) void seg_k1(
    const float* __restrict__ note,   // [B][F][E]
    const float* __restrict__ hv,     // [B][H][E]
    const float* __restrict__ W0,     // [12][12]
    const float* __restrict__ b0,     // [12]
    const float* __restrict__ W1,     // [12][12]
    const float* __restrict__ b1,     // [12]
    const float* __restrict__ Wc,     // [24][24]
    const float* __restrict__ bc,     // [24]
    float* __restrict__ num_t,
    float* __restrict__ den_t)
{
    const int blk = blockIdx.x;           // b*H + h
    const int b = blk / HH;
    const int h = blk - b * HH;
    const int tid = threadIdx.x;

    __shared__ float s_note[FF * EE];     // 12 KB, note[b] staged coalesced
    __shared__ float s_hcat[EE];
    __shared__ float s_q[EE];
    __shared__ float s_p[FF];
    __shared__ float s_pd[FF];
    __shared__ float s_wmax[2];

    const float* nb = note + (size_t)b * FF * EE;
    for (int i = tid; i < FF * EE; i += 128) s_note[i] = nb[i];

    const float* hvb = hv + ((size_t)b * HH + h) * EE;
    if (tid < C0C) {
        float acc = b0[tid];
        #pragma unroll
        for (int j = 0; j < C0C; ++j) acc += W0[tid * C0C + j] * hvb[j];
        s_hcat[tid] = acc;
    } else if (tid < 2 * C0C) {
        const int i = tid - C0C;
        float acc = b1[i];
        #pragma unroll
        for (int j = 0; j < C0C; ++j) acc += W1[i * C0C + j] * hvb[C0C + j];
        s_hcat[tid] = acc;
    }
    __syncthreads();
    if (tid < EE) {
        float acc = bc[tid];
        #pragma unroll
        for (int j = 0; j < EE; ++j) acc += Wc[tid * EE + j] * s_hcat[j];
        s_q[tid] = acc;
    }
    __syncthreads();

    // d_l for l = tid
    float d = 0.f;
    #pragma unroll
    for (int e = 0; e < EE; ++e) d += s_q[e] * s_note[tid * EE + e];

    const float scale = 0.20412414523193150818f;  // 1/sqrt(24)
    const float ds = d * scale;

    // block max of ds over 128 threads (2 waves)
    float m = ds;
    #pragma unroll
    for (int off = 32; off > 0; off >>= 1) m = fmaxf(m, __shfl_xor(m, off));
    if ((tid & 63) == 0) s_wmax[tid >> 6] = m;
    __syncthreads();
    m = fmaxf(s_wmax[0], s_wmax[1]);

    const float p = expf(ds - m);
    s_p[tid] = p;
    s_pd[tid] = p * d;
    __syncthreads();

    // Hillis-Steele inclusive scan over 128 elements, both arrays
    #pragma unroll
    for (int off = 1; off < FF; off <<= 1) {
        float a = 0.f, c = 0.f;
        if (tid >= off) { a = s_p[tid - off]; c = s_pd[tid - off]; }
        __syncthreads();
        s_p[tid] += a;
        s_pd[tid] += c;
        __syncthreads();
    }

    // write prefix tables: row (l+1) gets inclusive cumsum at l; row 0 is zero
    const size_t base = (size_t)b * (FF + 1) * HH + h;
    num_t[base + (size_t)(tid + 1) * HH] = s_pd[tid];
    den_t[base + (size_t)(tid + 1) * HH] = s_p[tid];
    if (tid == 0) {
        num_t[base] = 0.f;
        den_t[base] = 0.f;
    }
}

__global__ __launch_bounds__(256) void seg_k2(
    const float* __restrict__ num_t,
    const float* __restrict__ den_t,
    float* __restrict__ out)          // [B][F(s)][F(e)][H]
{
    const int blk = blockIdx.x;        // b*F + s
    const int b = blk >> 7;            // / 128
    const int s = blk & 127;
    const int tid = threadIdx.x;

    __shared__ float s_n0[HH];
    __shared__ float s_d0[HH];

    const float* nb = num_t + (size_t)b * (FF + 1) * HH;
    const float* db = den_t + (size_t)b * (FF + 1) * HH;
    if (tid < HH) {
        s_n0[tid] = nb[(size_t)s * HH + tid];
        s_d0[tid] = db[(size_t)s * HH + tid];
    }
    __syncthreads();

    float* ob = out + (size_t)blk * (FF * HH);

    // 4608 float4 chunks per (b,s) row; H=144 % 4 == 0 so chunks never cross e
    for (int i4 = tid; i4 < (FF * HH / 4); i4 += 256) {
        const int i = i4 * 4;
        const int e = i / HH;
        const int h = i - e * HH;
        float4 val = make_float4(0.f, 0.f, 0.f, 0.f);
        if (e >= s) {
            const float4 n1 = *reinterpret_cast<const float4*>(nb + (size_t)(e + 1) * HH + h);
            const float4 d1 = *reinterpret_cast<const float4*>(db + (size_t)(e + 1) * HH + h);
            const float4 n0 = *reinterpret_cast<const float4*>(&s_n0[h]);
            const float4 d0 = *reinterpret_cast<const float4*>(&s_d0[h]);
            val.x = (n1.x - n0.x) / (d1.x - d0.x);
            val.y = (n1.y - n0.y) / (d1.y - d0.y);
            val.z = (n1.z - n0.z) / (d1.z - d0.z);
            val.w = (n1.w - n0.w) / (d1.w - d0.w);
        }
        *reinterpret_cast<float4*>(ob + i) = val;
    }
}

extern "C" void kernel_launch(void* const* d_in, const int* in_sizes, int n_in,
                              void* d_out, int out_size, void* d_ws, size_t ws_size,
                              hipStream_t stream) {
    const float* note = (const float*)d_in[0];
    const float* hv   = (const float*)d_in[1];
    const float* W0   = (const float*)d_in[2];
    const float* b0   = (const float*)d_in[3];
    const float* W1   = (const float*)d_in[4];
    const float* b1   = (const float*)d_in[5];
    const float* Wc   = (const float*)d_in[6];
    const float* bc   = (const float*)d_in[7];
    float* out = (float*)d_out;

    float* num_t = (float*)d_ws;
    float* den_t = num_t + TABLE_ELEMS;

    seg_k1<<<BB * HH, 128, 0, stream>>>(note, hv, W0, b0, W1, b1, Wc, bc, num_t, den_t);
    seg_k2<<<BB * FF, 256, 0, stream>>>(num_t, den_t, out);
}